// Round 1
// baseline (115.160 us; speedup 1.0000x reference)
//
#include <hip/hip_runtime.h>
#include <cmath>
#include <complex>
#include <cstring>
#include <algorithm>

// ---------------- CG coefficient pack (computed on host, passed by value) ----

struct CGPack {
  float A0;          // (1,1,1) path 0x0->0
  float B[3][3];     // (1,3,3) -> [j][k]   0x1->1
  float C[5][5];     // (1,5,5) -> [j][k]   0x2->2
  float D[3][3];     // (3,1,3) -> [i][k]   1x0->1
  float E[3][3];     // (3,3,1) -> [i][j]   1x1->0
  float F[3][3][5];  // (3,3,5)             1x1->2
  float G[3][5][3];  // (3,5,3)             1x2->1
  float H[5][5];     // (5,1,5) -> [i][k]   2x0->2
  float I[5][3][3];  // (5,3,3)             2x1->1
  float J[5][5];     // (5,5,1) -> [i][j]   2x2->0
  float K[5][5][5];  // (5,5,5)             2x2->2
};

namespace {

using cd = std::complex<double>;

double factd(int n) { double r = 1.0; for (int i = 2; i <= n; ++i) r *= i; return r; }

double su2_cg(int j1, int m1, int j2, int m2, int j3, int m3) {
  if (m3 != m1 + m2) return 0.0;
  int vmin = std::max(std::max(-j1 + j2 + m3, -j1 + m1), 0);
  int vmax = std::min(std::min(j2 + j3 + m1, j3 - j1 + j2), j3 + m3);
  double C = std::sqrt((2.0 * j3 + 1.0) *
      factd(j3 + j1 - j2) * factd(j3 - j1 + j2) * factd(j1 + j2 - j3) *
      factd(j3 + m3) * factd(j3 - m3) /
      (factd(j1 + j2 + j3 + 1) * factd(j1 - m1) * factd(j1 + m1) *
       factd(j2 - m2) * factd(j2 + m2)));
  double S = 0.0;
  for (int v = vmin; v <= vmax; ++v) {
    double sgn = ((v + j2 + m2) & 1) ? -1.0 : 1.0;
    S += sgn * factd(j2 + j3 + m1 - v) * factd(j1 - m1 + v) /
         (factd(v) * factd(j3 - j1 + j2 - v) * factd(j3 + m3 - v) *
          factd(v + j1 - j2 - m3));
  }
  return C * S;
}

void real_to_complex(int l, cd q[5][5]) {
  for (int r = 0; r < 5; ++r)
    for (int c = 0; c < 5; ++c) q[r][c] = cd(0.0, 0.0);
  const double is2 = 1.0 / std::sqrt(2.0);
  for (int m = -l; m < 0; ++m) {
    q[l + m][l - m] = cd(is2, 0.0);   // col l+|m|
    q[l + m][l + m] = cd(0.0, -is2);  // col l-|m|
  }
  q[l][l] = cd(1.0, 0.0);
  for (int m = 1; m <= l; ++m) {
    double s = (m & 1) ? -1.0 : 1.0;
    q[l + m][l + m] = cd(s * is2, 0.0);
    q[l + m][l - m] = cd(0.0, s * is2);
  }
  cd f(1.0, 0.0);
  const cd mi(0.0, -1.0);
  for (int t = 0; t < l; ++t) f *= mi;
  for (int r = 0; r < 5; ++r)
    for (int c = 0; c < 5; ++c) q[r][c] *= f;
}

// dense real CG with component norm (== reference clebsch_gordan * sqrt(2*l3+1))
void compute_cg(int l1, int l2, int l3, float* out) {
  const int n1 = 2 * l1 + 1, n2 = 2 * l2 + 1, n3 = 2 * l3 + 1;
  double su2[5][5][5] = {};
  if (std::abs(l1 - l2) <= l3 && l3 <= l1 + l2) {
    for (int m1 = -l1; m1 <= l1; ++m1)
      for (int m2 = -l2; m2 <= l2; ++m2)
        if (std::abs(m1 + m2) <= l3)
          su2[l1 + m1][l2 + m2][l3 + m1 + m2] = su2_cg(l1, m1, l2, m2, l3, m1 + m2);
  }
  const double norm = 1.0 / std::sqrt(2.0 * l3 + 1.0);       // from _su2_cg_mat
  const double comp = std::sqrt(2.0 * l3 + 1.0);             // component norm
  cd q1[5][5], q2[5][5], q3[5][5];
  real_to_complex(l1, q1);
  real_to_complex(l2, q2);
  real_to_complex(l3, q3);
  for (int j = 0; j < n1; ++j)
    for (int ll = 0; ll < n2; ++ll)
      for (int m = 0; m < n3; ++m) {
        cd acc(0.0, 0.0);
        for (int i = 0; i < n1; ++i)
          for (int k = 0; k < n2; ++k)
            for (int n = 0; n < n3; ++n)
              acc += q1[i][j] * q2[k][ll] * std::conj(q3[n][m]) * su2[i][k][n];
        out[(j * n2 + ll) * n3 + m] = (float)(acc.real() * norm * comp);
      }
}

CGPack make_pack() {
  CGPack p;
  float t[125];
  compute_cg(0, 0, 0, t); p.A0 = t[0];
  compute_cg(0, 1, 1, t); std::memcpy(p.B, t, 9 * sizeof(float));
  compute_cg(0, 2, 2, t); std::memcpy(p.C, t, 25 * sizeof(float));
  compute_cg(1, 0, 1, t); std::memcpy(p.D, t, 9 * sizeof(float));
  compute_cg(1, 1, 0, t); std::memcpy(p.E, t, 9 * sizeof(float));
  compute_cg(1, 1, 2, t); std::memcpy(p.F, t, 45 * sizeof(float));
  compute_cg(1, 2, 1, t); std::memcpy(p.G, t, 45 * sizeof(float));
  compute_cg(2, 0, 2, t); std::memcpy(p.H, t, 25 * sizeof(float));
  compute_cg(2, 1, 1, t); std::memcpy(p.I, t, 45 * sizeof(float));
  compute_cg(2, 2, 0, t); std::memcpy(p.J, t, 25 * sizeof(float));
  compute_cg(2, 2, 2, t); std::memcpy(p.K, t, 125 * sizeof(float));
  return p;
}

}  // namespace

// ---------------- kernel ------------------------------------------------------

__device__ __forceinline__ float ntload(const float* p) {
  return __builtin_nontemporal_load(p);
}
__device__ __forceinline__ void ntstore(float* p, float v) {
  __builtin_nontemporal_store(v, p);
}

__global__ __launch_bounds__(256) void tp_kernel(
    const float* __restrict__ in1, const float* __restrict__ in2,
    float* __restrict__ out, CGPack cg) {
  const int gid = blockIdx.x * 256 + threadIdx.x;
  const int b = gid >> 7;
  const int u = gid & 127;
  const float* r1 = in1 + (size_t)b * 1152;
  const float* r2 = in2 + (size_t)b * 9;

  // ---- load inputs
  const float a0 = ntload(r1 + u);
  float a1[3], a2[5], b1[3], b2[5];
#pragma unroll
  for (int i = 0; i < 3; ++i) a1[i] = ntload(r1 + 128 + 3 * u + i);
#pragma unroll
  for (int i = 0; i < 5; ++i) a2[i] = ntload(r1 + 512 + 5 * u + i);
  const float b0 = r2[0];
#pragma unroll
  for (int j = 0; j < 3; ++j) b1[j] = r2[1 + j];
#pragma unroll
  for (int j = 0; j < 5; ++j) b2[j] = r2[4 + j];

  float* ro = out + (size_t)b * 4480;

  // ---- l3 = 0 chunks (A, E, J), one scalar each
  float oA = a0 * b0 * cg.A0;
  float oE = 0.f, oJ = 0.f;
#pragma unroll
  for (int i = 0; i < 3; ++i)
#pragma unroll
    for (int j = 0; j < 3; ++j) oE += a1[i] * b1[j] * cg.E[i][j];
#pragma unroll
  for (int i = 0; i < 5; ++i)
#pragma unroll
    for (int j = 0; j < 5; ++j) oJ += a2[i] * b2[j] * cg.J[i][j];
  ntstore(ro + u, oA);
  ntstore(ro + 128 + u, oE);
  ntstore(ro + 256 + u, oJ);

  // ---- l3 = 1 chunks (B, D, G, I), 3 scalars each
  float oB[3] = {}, oD[3] = {}, oG[3] = {}, oI[3] = {};
#pragma unroll
  for (int j = 0; j < 3; ++j)
#pragma unroll
    for (int k = 0; k < 3; ++k) oB[k] += a0 * b1[j] * cg.B[j][k];
#pragma unroll
  for (int i = 0; i < 3; ++i)
#pragma unroll
    for (int k = 0; k < 3; ++k) oD[k] += a1[i] * b0 * cg.D[i][k];
#pragma unroll
  for (int i = 0; i < 3; ++i)
#pragma unroll
    for (int j = 0; j < 5; ++j) {
      const float p = a1[i] * b2[j];
#pragma unroll
      for (int k = 0; k < 3; ++k) oG[k] += p * cg.G[i][j][k];
    }
#pragma unroll
  for (int i = 0; i < 5; ++i)
#pragma unroll
    for (int j = 0; j < 3; ++j) {
      const float p = a2[i] * b1[j];
#pragma unroll
      for (int k = 0; k < 3; ++k) oI[k] += p * cg.I[i][j][k];
    }
#pragma unroll
  for (int k = 0; k < 3; ++k) {
    ntstore(ro + 384 + 3 * u + k, oB[k]);
    ntstore(ro + 768 + 3 * u + k, oD[k]);
    ntstore(ro + 1152 + 3 * u + k, oG[k]);
    ntstore(ro + 1536 + 3 * u + k, oI[k]);
  }

  // ---- l3 = 2 chunks (C, F, H, K), 5 scalars each
  float oC[5] = {}, oF[5] = {}, oH[5] = {}, oK[5] = {};
#pragma unroll
  for (int j = 0; j < 5; ++j)
#pragma unroll
    for (int k = 0; k < 5; ++k) oC[k] += a0 * b2[j] * cg.C[j][k];
#pragma unroll
  for (int i = 0; i < 3; ++i)
#pragma unroll
    for (int j = 0; j < 3; ++j) {
      const float p = a1[i] * b1[j];
#pragma unroll
      for (int k = 0; k < 5; ++k) oF[k] += p * cg.F[i][j][k];
    }
#pragma unroll
  for (int i = 0; i < 5; ++i)
#pragma unroll
    for (int k = 0; k < 5; ++k) oH[k] += a2[i] * b0 * cg.H[i][k];
#pragma unroll
  for (int i = 0; i < 5; ++i)
#pragma unroll
    for (int j = 0; j < 5; ++j) {
      const float p = a2[i] * b2[j];
#pragma unroll
      for (int k = 0; k < 5; ++k) oK[k] += p * cg.K[i][j][k];
    }
#pragma unroll
  for (int k = 0; k < 5; ++k) {
    ntstore(ro + 1920 + 5 * u + k, oC[k]);
    ntstore(ro + 2560 + 5 * u + k, oF[k]);
    ntstore(ro + 3200 + 5 * u + k, oH[k]);
    ntstore(ro + 3840 + 5 * u + k, oK[k]);
  }
}

// ---------------- launch ------------------------------------------------------

extern "C" void kernel_launch(void* const* d_in, const int* in_sizes, int n_in,
                              void* d_out, int out_size, void* d_ws, size_t ws_size,
                              hipStream_t stream) {
  const float* in1 = (const float*)d_in[0];
  const float* in2 = (const float*)d_in[1];
  float* out = (float*)d_out;

  const CGPack pack = make_pack();  // pure host math, deterministic, capture-safe

  const int B = in_sizes[0] / 1152;  // 16384
  const int total_threads = B * 128;
  const int blocks = (total_threads + 255) / 256;

  hipLaunchKernelGGL(tp_kernel, dim3(blocks), dim3(256), 0, stream,
                     in1, in2, out, pack);
}

// Round 3
// 63.801 us; speedup vs baseline: 1.8050x; 1.8050x over previous
//
#include <hip/hip_runtime.h>
#include <cmath>
#include <complex>
#include <cstring>
#include <algorithm>

typedef float f32x4 __attribute__((ext_vector_type(4)));

// ---------------- CG coefficient pack (computed on host, passed by value) ----

struct CGPack {
  float A0;          // (1,1,1) path 0x0->0
  float B[3][3];     // (1,3,3) -> [j][k]   0x1->1
  float C[5][5];     // (1,5,5) -> [j][k]   0x2->2
  float D[3][3];     // (3,1,3) -> [i][k]   1x0->1
  float E[3][3];     // (3,3,1) -> [i][j]   1x1->0
  float F[3][3][5];  // (3,3,5)             1x1->2
  float G[3][5][3];  // (3,5,3)             1x2->1
  float H[5][5];     // (5,1,5) -> [i][k]   2x0->2
  float I[5][3][3];  // (5,3,3)             2x1->1
  float J[5][5];     // (5,5,1) -> [i][j]   2x2->0
  float K[5][5][5];  // (5,5,5)             2x2->2
};

namespace {

using cd = std::complex<double>;

double factd(int n) { double r = 1.0; for (int i = 2; i <= n; ++i) r *= i; return r; }

double su2_cg(int j1, int m1, int j2, int m2, int j3, int m3) {
  if (m3 != m1 + m2) return 0.0;
  int vmin = std::max(std::max(-j1 + j2 + m3, -j1 + m1), 0);
  int vmax = std::min(std::min(j2 + j3 + m1, j3 - j1 + j2), j3 + m3);
  double C = std::sqrt((2.0 * j3 + 1.0) *
      factd(j3 + j1 - j2) * factd(j3 - j1 + j2) * factd(j1 + j2 - j3) *
      factd(j3 + m3) * factd(j3 - m3) /
      (factd(j1 + j2 + j3 + 1) * factd(j1 - m1) * factd(j1 + m1) *
       factd(j2 - m2) * factd(j2 + m2)));
  double S = 0.0;
  for (int v = vmin; v <= vmax; ++v) {
    double sgn = ((v + j2 + m2) & 1) ? -1.0 : 1.0;
    S += sgn * factd(j2 + j3 + m1 - v) * factd(j1 - m1 + v) /
         (factd(v) * factd(j3 - j1 + j2 - v) * factd(j3 + m3 - v) *
          factd(v + j1 - j2 - m3));
  }
  return C * S;
}

void real_to_complex(int l, cd q[5][5]) {
  for (int r = 0; r < 5; ++r)
    for (int c = 0; c < 5; ++c) q[r][c] = cd(0.0, 0.0);
  const double is2 = 1.0 / std::sqrt(2.0);
  for (int m = -l; m < 0; ++m) {
    q[l + m][l - m] = cd(is2, 0.0);   // col l+|m|
    q[l + m][l + m] = cd(0.0, -is2);  // col l-|m|
  }
  q[l][l] = cd(1.0, 0.0);
  for (int m = 1; m <= l; ++m) {
    double s = (m & 1) ? -1.0 : 1.0;
    q[l + m][l + m] = cd(s * is2, 0.0);
    q[l + m][l - m] = cd(0.0, s * is2);
  }
  cd f(1.0, 0.0);
  const cd mi(0.0, -1.0);
  for (int t = 0; t < l; ++t) f *= mi;
  for (int r = 0; r < 5; ++r)
    for (int c = 0; c < 5; ++c) q[r][c] *= f;
}

// dense real CG with component norm (== reference clebsch_gordan * sqrt(2*l3+1))
void compute_cg(int l1, int l2, int l3, float* out) {
  const int n1 = 2 * l1 + 1, n2 = 2 * l2 + 1, n3 = 2 * l3 + 1;
  double su2[5][5][5] = {};
  if (std::abs(l1 - l2) <= l3 && l3 <= l1 + l2) {
    for (int m1 = -l1; m1 <= l1; ++m1)
      for (int m2 = -l2; m2 <= l2; ++m2)
        if (std::abs(m1 + m2) <= l3)
          su2[l1 + m1][l2 + m2][l3 + m1 + m2] = su2_cg(l1, m1, l2, m2, l3, m1 + m2);
  }
  const double norm = 1.0 / std::sqrt(2.0 * l3 + 1.0);       // from _su2_cg_mat
  const double comp = std::sqrt(2.0 * l3 + 1.0);             // component norm
  cd q1[5][5], q2[5][5], q3[5][5];
  real_to_complex(l1, q1);
  real_to_complex(l2, q2);
  real_to_complex(l3, q3);
  for (int j = 0; j < n1; ++j)
    for (int ll = 0; ll < n2; ++ll)
      for (int m = 0; m < n3; ++m) {
        cd acc(0.0, 0.0);
        for (int i = 0; i < n1; ++i)
          for (int k = 0; k < n2; ++k)
            for (int n = 0; n < n3; ++n)
              acc += q1[i][j] * q2[k][ll] * std::conj(q3[n][m]) * su2[i][k][n];
        out[(j * n2 + ll) * n3 + m] = (float)(acc.real() * norm * comp);
      }
}

CGPack make_pack() {
  CGPack p;
  float t[125];
  compute_cg(0, 0, 0, t); p.A0 = t[0];
  compute_cg(0, 1, 1, t); std::memcpy(p.B, t, 9 * sizeof(float));
  compute_cg(0, 2, 2, t); std::memcpy(p.C, t, 25 * sizeof(float));
  compute_cg(1, 0, 1, t); std::memcpy(p.D, t, 9 * sizeof(float));
  compute_cg(1, 1, 0, t); std::memcpy(p.E, t, 9 * sizeof(float));
  compute_cg(1, 1, 2, t); std::memcpy(p.F, t, 45 * sizeof(float));
  compute_cg(1, 2, 1, t); std::memcpy(p.G, t, 45 * sizeof(float));
  compute_cg(2, 0, 2, t); std::memcpy(p.H, t, 25 * sizeof(float));
  compute_cg(2, 1, 1, t); std::memcpy(p.I, t, 45 * sizeof(float));
  compute_cg(2, 2, 0, t); std::memcpy(p.J, t, 25 * sizeof(float));
  compute_cg(2, 2, 2, t); std::memcpy(p.K, t, 125 * sizeof(float));
  return p;
}

}  // namespace

// ---------------- kernel ------------------------------------------------------
//
// Block = 256 threads = 2 batch rows (128 u-channels each).
// Compute into an LDS out-stage (2 x 4480 floats = 35840 B), then store the
// whole 2-row region as contiguous float4 nontemporal stores (full-line,
// coalesced). Loads are plain (L1 absorbs the stride-3/5 partial-line reuse).

__global__ __launch_bounds__(256) void tp_kernel(
    const float* __restrict__ in1, const float* __restrict__ in2,
    float* __restrict__ out, CGPack cg, int Btot) {
  __shared__ float smem[8960];  // 2 rows x 4480

  const int t = threadIdx.x;
  const int row = t >> 7;   // 0 or 1
  const int u = t & 127;
  const long long b = (long long)blockIdx.x * 2 + row;

  if (b < Btot) {
    const float* r1 = in1 + (size_t)b * 1152;
    const float* r2 = in2 + (size_t)b * 9;
    float* so = smem + row * 4480;

    // ---- load inputs (plain loads; L1 handles stride-3/5 line reuse)
    const float a0 = r1[u];
    float a1[3], a2[5], b1[3], b2[5];
#pragma unroll
    for (int i = 0; i < 3; ++i) a1[i] = r1[128 + 3 * u + i];
#pragma unroll
    for (int i = 0; i < 5; ++i) a2[i] = r1[512 + 5 * u + i];
    const float b0 = r2[0];
#pragma unroll
    for (int j = 0; j < 3; ++j) b1[j] = r2[1 + j];
#pragma unroll
    for (int j = 0; j < 5; ++j) b2[j] = r2[4 + j];

    // ---- l3 = 0 chunks (A, E, J)
    float oA = a0 * b0 * cg.A0;
    float oE = 0.f, oJ = 0.f;
#pragma unroll
    for (int i = 0; i < 3; ++i)
#pragma unroll
      for (int j = 0; j < 3; ++j) oE += a1[i] * b1[j] * cg.E[i][j];
#pragma unroll
    for (int i = 0; i < 5; ++i)
#pragma unroll
      for (int j = 0; j < 5; ++j) oJ += a2[i] * b2[j] * cg.J[i][j];
    so[u] = oA;
    so[128 + u] = oE;
    so[256 + u] = oJ;

    // ---- l3 = 1 chunks (B, D, G, I)
    float oB[3] = {}, oD[3] = {}, oG[3] = {}, oI[3] = {};
#pragma unroll
    for (int j = 0; j < 3; ++j)
#pragma unroll
      for (int k = 0; k < 3; ++k) oB[k] += a0 * b1[j] * cg.B[j][k];
#pragma unroll
    for (int i = 0; i < 3; ++i)
#pragma unroll
      for (int k = 0; k < 3; ++k) oD[k] += a1[i] * b0 * cg.D[i][k];
#pragma unroll
    for (int i = 0; i < 3; ++i)
#pragma unroll
      for (int j = 0; j < 5; ++j) {
        const float p = a1[i] * b2[j];
#pragma unroll
        for (int k = 0; k < 3; ++k) oG[k] += p * cg.G[i][j][k];
      }
#pragma unroll
    for (int i = 0; i < 5; ++i)
#pragma unroll
      for (int j = 0; j < 3; ++j) {
        const float p = a2[i] * b1[j];
#pragma unroll
        for (int k = 0; k < 3; ++k) oI[k] += p * cg.I[i][j][k];
      }
#pragma unroll
    for (int k = 0; k < 3; ++k) {
      so[384 + 3 * u + k] = oB[k];
      so[768 + 3 * u + k] = oD[k];
      so[1152 + 3 * u + k] = oG[k];
      so[1536 + 3 * u + k] = oI[k];
    }

    // ---- l3 = 2 chunks (C, F, H, K)
    float oC[5] = {}, oF[5] = {}, oH[5] = {}, oK[5] = {};
#pragma unroll
    for (int j = 0; j < 5; ++j)
#pragma unroll
      for (int k = 0; k < 5; ++k) oC[k] += a0 * b2[j] * cg.C[j][k];
#pragma unroll
    for (int i = 0; i < 3; ++i)
#pragma unroll
      for (int j = 0; j < 3; ++j) {
        const float p = a1[i] * b1[j];
#pragma unroll
        for (int k = 0; k < 5; ++k) oF[k] += p * cg.F[i][j][k];
      }
#pragma unroll
    for (int i = 0; i < 5; ++i)
#pragma unroll
      for (int k = 0; k < 5; ++k) oH[k] += a2[i] * b0 * cg.H[i][k];
#pragma unroll
    for (int i = 0; i < 5; ++i)
#pragma unroll
      for (int j = 0; j < 5; ++j) {
        const float p = a2[i] * b2[j];
#pragma unroll
        for (int k = 0; k < 5; ++k) oK[k] += p * cg.K[i][j][k];
      }
#pragma unroll
    for (int k = 0; k < 5; ++k) {
      so[1920 + 5 * u + k] = oC[k];
      so[2560 + 5 * u + k] = oF[k];
      so[3200 + 5 * u + k] = oH[k];
      so[3840 + 5 * u + k] = oK[k];
    }
  }

  __syncthreads();

  // ---- cooperative contiguous float4 nontemporal store of both rows
  const long long rows_left = (long long)Btot - (long long)blockIdx.x * 2;
  const int nvec = (rows_left >= 2) ? 2240 : (rows_left == 1 ? 1120 : 0);
  const f32x4* s4 = reinterpret_cast<const f32x4*>(smem);
  f32x4* o4 = reinterpret_cast<f32x4*>(out + (size_t)blockIdx.x * 8960);
  for (int i = t; i < nvec; i += 256)
    __builtin_nontemporal_store(s4[i], o4 + i);
}

// ---------------- launch ------------------------------------------------------

extern "C" void kernel_launch(void* const* d_in, const int* in_sizes, int n_in,
                              void* d_out, int out_size, void* d_ws, size_t ws_size,
                              hipStream_t stream) {
  const float* in1 = (const float*)d_in[0];
  const float* in2 = (const float*)d_in[1];
  float* out = (float*)d_out;

  const CGPack pack = make_pack();  // pure host math, deterministic, capture-safe

  const int B = in_sizes[0] / 1152;  // 16384
  const int blocks = (B + 1) / 2;

  hipLaunchKernelGGL(tp_kernel, dim3(blocks), dim3(256), 0, stream,
                     in1, in2, out, pack, B);
}